// Round 1
// baseline (148.397 us; speedup 1.0000x reference)
//
#include <hip/hip_runtime.h>

#define B_ 2
#define L_ 256
#define D_ 512
#define H_ 8
#define DV_ 64
#define NEGINF 1e12f

// ws layout (floats):
//   value : [B][H][L][DV]  = 262144
//   WR    : [512][8]       = 4096
//   s_src : [B][H][L]      = 4096
//   s_tgt : [B][H][L]      = 4096
#define WS_VALUE 0
#define WS_WR    262144
#define WS_SSRC  266240
#define WS_STGT  270336

// ---------------- Kernel A: WR[k][h] = sum_d W_relation[k][h*64+d] * w_rel[h][d]
__global__ __launch_bounds__(256) void k_wr(const float* __restrict__ Wrel,
                                            const float* __restrict__ wrel,
                                            float* __restrict__ WR) {
    int flat = blockIdx.x * 256 + threadIdx.x;   // 4096 = 512*8
    int k = flat >> 3, h = flat & 7;
    const float* a = Wrel + k * 512 + h * 64;
    const float* b = wrel + h * 64;
    float s = 0.f;
#pragma unroll
    for (int d = 0; d < 64; d += 4) {
        float4 x = *(const float4*)(a + d);
        float4 y = *(const float4*)(b + d);
        s += x.x * y.x + x.y * y.y + x.z * y.z + x.w * y.w;
    }
    WR[k * 8 + h] = s;
}

// ---------------- Kernel B: value[b][h][l][dv] = sum_k inp[b][l][k] * W_value[k][h*64+dv]
__global__ __launch_bounds__(256) void k_value(const float* __restrict__ inp,
                                               const float* __restrict__ Wv,
                                               float* __restrict__ value) {
    int blk = blockIdx.x;          // 256 blocks = 128 row-tiles x 2 col-halves
    int ct  = blk & 1;
    int rt  = blk >> 1;            // 4 flat rows per tile (flat row = b*L + l)
    int n   = ct * 256 + threadIdx.x;   // output col 0..511
    int r0  = rt * 4;
    const float* i0 = inp + (size_t)(r0 + 0) * 512;
    const float* i1 = inp + (size_t)(r0 + 1) * 512;
    const float* i2 = inp + (size_t)(r0 + 2) * 512;
    const float* i3 = inp + (size_t)(r0 + 3) * 512;
    float a0 = 0.f, a1 = 0.f, a2 = 0.f, a3 = 0.f;
    for (int k = 0; k < 512; ++k) {
        float w = Wv[(size_t)k * 512 + n];
        a0 = fmaf(i0[k], w, a0);
        a1 = fmaf(i1[k], w, a1);
        a2 = fmaf(i2[k], w, a2);
        a3 = fmaf(i3[k], w, a3);
    }
    int h = n >> 6, dv = n & 63;
    float acc[4] = {a0, a1, a2, a3};
#pragma unroll
    for (int r = 0; r < 4; ++r) {
        int row = r0 + r;
        int b = row >> 8, l = row & 255;
        value[(((size_t)(b * 8 + h)) * 256 + l) * 64 + dv] = acc[r];
    }
}

// ---------------- Kernel C: s_src/s_tgt[b][h][j] = dot(value[b][h][j][:], w_{src,tgt}[h][:])
__global__ __launch_bounds__(256) void k_src_tgt(const float* __restrict__ value,
                                                 const float* __restrict__ wsrc,
                                                 const float* __restrict__ wtgt,
                                                 float* __restrict__ s_src,
                                                 float* __restrict__ s_tgt) {
    int flat = blockIdx.x * 256 + threadIdx.x;   // 4096 = (b*8+h)*256 + j
    int h = (flat >> 8) & 7;
    const float* v  = value + (size_t)flat * 64;
    const float* ws = wsrc + h * 64;
    const float* wt = wtgt + h * 64;
    float ss = 0.f, st = 0.f;
#pragma unroll
    for (int d = 0; d < 64; d += 4) {
        float4 x = *(const float4*)(v + d);
        float4 s4 = *(const float4*)(ws + d);
        float4 t4 = *(const float4*)(wt + d);
        ss += x.x * s4.x + x.y * s4.y + x.z * s4.z + x.w * s4.w;
        st += x.x * t4.x + x.y * t4.y + x.z * t4.z + x.w * t4.w;
    }
    s_src[flat] = ss;
    s_tgt[flat] = st;
}

// ---------------- Kernel D: fused s_rel + scores + softmax + attn fixups + out
__global__ __launch_bounds__(256) void k_main(const float* __restrict__ rel,    // [b][i][j][k]
                                              const int*   __restrict__ mask,   // [b][i][j]
                                              const float* __restrict__ adj,    // [b][h][i][j]
                                              const float* __restrict__ inp,    // [b][i][D]
                                              const float* __restrict__ value,  // [b][h][j][dv]
                                              const float* __restrict__ WR,     // [k][h]
                                              const float* __restrict__ s_src,  // [b][h][j]
                                              const float* __restrict__ s_tgt,  // [b][h][i]
                                              float* __restrict__ out) {        // [b][i][D]
    __shared__ float srel[8][256];
    __shared__ float attn[8][256];
    int bi  = blockIdx.x;           // b*256 + i
    int b   = bi >> 8;
    int i   = bi & 255;
    int tid = threadIdx.x;

    // ---- Phase 1: srel[h][j], lane owns j = tid, accumulates over k with uniform WR
    {
        const float* r = rel + ((size_t)bi * 256 + tid) * 512;
        float acc[8];
#pragma unroll
        for (int h = 0; h < 8; ++h) acc[h] = 0.f;
        for (int kk = 0; kk < 512; kk += 4) {
            float4 v = *(const float4*)(r + kk);
            const float* w = WR + kk * 8;    // wave-uniform -> scalar loads
#pragma unroll
            for (int h = 0; h < 8; ++h) {
                acc[h] = fmaf(v.x, w[h],
                         fmaf(v.y, w[8 + h],
                         fmaf(v.z, w[16 + h],
                         fmaf(v.w, w[24 + h], acc[h]))));
            }
        }
#pragma unroll
        for (int h = 0; h < 8; ++h) srel[h][tid] = acc[h];
    }
    __syncthreads();

    // ---- Phase 2: per (h) row softmax over j; 32 lanes per h, 8 j per lane
    {
        int h  = tid >> 5;
        int ln = tid & 31;
        float stgt = s_tgt[(size_t)(b * 8 + h) * 256 + i];
        const float* ssrc   = s_src + (size_t)(b * 8 + h) * 256;
        const float* adjrow = adj + ((size_t)(b * 8 + h) * 256 + i) * 256;
        const int*   mrow   = mask + (size_t)bi * 256;

        float sc[8], av[8];
        int mb = 0;
        float rowmax = -3.0e38f;
#pragma unroll
        for (int t = 0; t < 8; ++t) {
            int j = ln + 32 * t;
            float a = adjrow[j];
            av[t] = a;
            int m = mrow[j];
            float s = ssrc[j] + stgt + srel[h][j];
            s = (s >= 0.f) ? s : 0.2f * s;     // leaky relu on the sum
            if (m != 0) { s = -NEGINF; mb |= (1 << t); }
            if (a == 0.f) s = -NEGINF;
            sc[t] = s;
            rowmax = fmaxf(rowmax, s);
        }
#pragma unroll
        for (int off = 16; off >= 1; off >>= 1)
            rowmax = fmaxf(rowmax, __shfl_xor(rowmax, off));

        float rowsum = 0.f;
#pragma unroll
        for (int t = 0; t < 8; ++t) {
            sc[t] = expf(sc[t] - rowmax);
            rowsum += sc[t];
        }
#pragma unroll
        for (int off = 16; off >= 1; off >>= 1)
            rowsum += __shfl_xor(rowsum, off);

        float sumabs = 0.f;
#pragma unroll
        for (int t = 0; t < 8; ++t) {
            float p = sc[t] / rowsum;
            float invv = (av[t] == 0.f) ? 1e-12f : (1.0f / av[t]);
            p *= invv;
            sc[t] = p;
            sumabs += fabsf(p);
        }
#pragma unroll
        for (int off = 16; off >= 1; off >>= 1)
            sumabs += __shfl_xor(sumabs, off);

        float rdn = 1.0f / fmaxf(sumabs, 1e-12f);
#pragma unroll
        for (int t = 0; t < 8; ++t) {
            float p = sc[t] * rdn;
            if (mb & (1 << t)) p = 0.f;
            if (av[t] == 0.f) p = 0.f;
            attn[h][ln + 32 * t] = p;
        }
    }
    __syncthreads();

    // ---- Phase 3: out[b][i][h*64+d] = inp + sum_j attn[h][j] * value[b][h][j][d]
    {
        int h  = tid >> 5;
        int d0 = (tid & 31) * 2;
        const float* vbase = value + ((size_t)(b * 8 + h) * 256) * 64 + d0;
        float ax = 0.f, ay = 0.f;
        for (int j = 0; j < 256; ++j) {
            float a = attn[h][j];
            float2 v2 = *(const float2*)(vbase + (size_t)j * 64);
            ax = fmaf(a, v2.x, ax);
            ay = fmaf(a, v2.y, ay);
        }
        size_t o = (size_t)bi * 512 + h * 64 + d0;
        out[o]     = inp[o] + ax;
        out[o + 1] = inp[o + 1] + ay;
    }
}

extern "C" void kernel_launch(void* const* d_in, const int* in_sizes, int n_in,
                              void* d_out, int out_size, void* d_ws, size_t ws_size,
                              hipStream_t stream) {
    const float* inp      = (const float*)d_in[0];
    const float* rel      = (const float*)d_in[1];
    const int*   mask     = (const int*)  d_in[2];
    const float* adj      = (const float*)d_in[3];
    const float* W_value  = (const float*)d_in[4];
    const float* W_rel    = (const float*)d_in[5];
    const float* w_src    = (const float*)d_in[6];
    const float* w_tgt    = (const float*)d_in[7];
    const float* w_rel    = (const float*)d_in[8];
    float* out = (float*)d_out;

    float* ws    = (float*)d_ws;
    float* value = ws + WS_VALUE;
    float* WR    = ws + WS_WR;
    float* s_src = ws + WS_SSRC;
    float* s_tgt = ws + WS_STGT;

    k_wr<<<16, 256, 0, stream>>>(W_rel, w_rel, WR);
    k_value<<<256, 256, 0, stream>>>(inp, W_value, value);
    k_src_tgt<<<16, 256, 0, stream>>>(value, w_src, w_tgt, s_src, s_tgt);
    k_main<<<B_ * L_, 256, 0, stream>>>(rel, mask, adj, inp, value, WR,
                                        s_src, s_tgt, out);
}